// Round 1
// baseline (65.460 us; speedup 1.0000x reference)
//
#include <hip/hip_runtime.h>

#define N 4096
#define ROWS_PER_BLOCK 16
#define NBLOCKS (N / ROWS_PER_BLOCK)   // 256 blocks
#define THREADS 512                    // 8 waves/block
#define CHUNKS (THREADS / ROWS_PER_BLOCK)  // 32 j-combs
#define JPT (N / CHUNKS)               // 128 j-iterations per thread
#define NOTCH_THRESH 2.0f

// Full-matrix pairwise penalty; upper-triangle sum recovered as
// (full_sum - 4*N) * 0.5  (diagonal pair has d=0 -> penalty^2 = 4).
__global__ __launch_bounds__(THREADS) void notch_main(
    const float* __restrict__ pos,
    const float* __restrict__ sx,
    const float* __restrict__ sy,
    float* __restrict__ partial)
{
    // tile[j] = {x_j, y_j, sx_j/2, sy_j/2}
    __shared__ float4 tile[N];                 // 64 KB
    __shared__ float red[THREADS / 64];

    const int tid = threadIdx.x;

    // Stage all inputs into LDS (coalesced global reads, contiguous b128 writes)
    for (int j = tid; j < N; j += THREADS) {
        float4 t;
        t.x = pos[j];          // x
        t.y = pos[N + j];      // y  (NUM_PHYS == N)
        t.z = 0.5f * sx[j];    // half width
        t.w = 0.5f * sy[j];    // half height
        tile[j] = t;
    }
    __syncthreads();

    const int i_local = tid & (ROWS_PER_BLOCK - 1);
    const int chunk   = tid >> 4;              // 0..31; within a wave: 4 values, 16-lane broadcast
    const int i       = blockIdx.x * ROWS_PER_BLOCK + i_local;

    const float4 me = tile[i];
    float acc = 0.0f;

    // j = jj*32 + chunk: 4 distinct b128 addrs per wave hitting disjoint bank
    // quads (bank = 4*chunk mod 32) -> conflict-free, broadcast within groups.
    #pragma unroll 4
    for (int jj = 0; jj < JPT; ++jj) {
        const int j = jj * CHUNKS + chunk;
        const float4 t = tile[j];
        float dx = fabsf(me.x - t.x) - (me.z + t.z);
        float dy = fabsf(me.y - t.y) - (me.w + t.w);
        float d  = fmaxf(dx, 0.0f) + fmaxf(dy, 0.0f);
        float p  = fmaxf(NOTCH_THRESH - d, 0.0f);
        acc = fmaf(p, p, acc);
    }

    // Deterministic reduction: wave shuffle -> LDS -> per-block partial
    for (int off = 32; off > 0; off >>= 1)
        acc += __shfl_down(acc, off, 64);
    const int wave = tid >> 6;
    const int lane = tid & 63;
    if (lane == 0) red[wave] = acc;
    __syncthreads();
    if (tid == 0) {
        float s = 0.0f;
        #pragma unroll
        for (int w = 0; w < THREADS / 64; ++w) s += red[w];
        partial[blockIdx.x] = s;
    }
}

__global__ __launch_bounds__(256) void notch_final(
    const float* __restrict__ partial, float* __restrict__ out)
{
    __shared__ float red[4];
    const int tid = threadIdx.x;
    float v = partial[tid];   // exactly 256 partials
    for (int off = 32; off > 0; off >>= 1)
        v += __shfl_down(v, off, 64);
    if ((tid & 63) == 0) red[tid >> 6] = v;
    __syncthreads();
    if (tid == 0) {
        const float total = red[0] + red[1] + red[2] + red[3];
        out[0] = (total - 4.0f * (float)N) * 0.5f;
    }
}

extern "C" void kernel_launch(void* const* d_in, const int* in_sizes, int n_in,
                              void* d_out, int out_size, void* d_ws, size_t ws_size,
                              hipStream_t stream) {
    const float* pos = (const float*)d_in[0];
    // d_in[1] = macro_mask (unused by the reference computation)
    const float* sx  = (const float*)d_in[2];
    const float* sy  = (const float*)d_in[3];
    float* out     = (float*)d_out;
    float* partial = (float*)d_ws;   // 256 floats of scratch

    notch_main<<<NBLOCKS, THREADS, 0, stream>>>(pos, sx, sy, partial);
    notch_final<<<1, 256, 0, stream>>>(partial, out);
}

// Round 2
// 65.107 us; speedup vs baseline: 1.0054x; 1.0054x over previous
//
#include <hip/hip_runtime.h>

#define N 4096
#define ROWS_PER_BLOCK 16
#define NBLOCKS (N / ROWS_PER_BLOCK)   // 256 blocks = 1 per CU
#define THREADS 512                    // 8 waves/block
#define R 4                            // rows per thread (LDS reuse factor)
#define CCHUNKS (THREADS / R)          // 128 j-chunks
#define JPT (N / CCHUNKS)              // 32 j-iterations per thread
#define NOTCH_THRESH 2.0f

// Full-matrix pairwise penalty; upper-triangle sum recovered as
// (full_sum - 4*N) * 0.5  (diagonal pair has d=0 -> penalty^2 = 4).
// Each thread owns R=4 consecutive rows so one LDS read of tile[j]
// feeds 4 pair computations (LDS pipe was the binding resource).
__global__ __launch_bounds__(THREADS) void notch_main(
    const float* __restrict__ pos,
    const float* __restrict__ sx,
    const float* __restrict__ sy,
    float* __restrict__ partial)
{
    // tile[j] = {x_j, y_j, sx_j/2, sy_j/2}
    __shared__ float4 tile[N];                 // 64 KB
    __shared__ float red[THREADS / 64];

    const int tid = threadIdx.x;

    // Stage all inputs into LDS (coalesced global reads)
    for (int j = tid; j < N; j += THREADS) {
        float4 t;
        t.x = pos[j];          // x
        t.y = pos[N + j];      // y  (NUM_PHYS == N)
        t.z = 0.5f * sx[j];    // half width
        t.w = 0.5f * sy[j];    // half height
        tile[j] = t;
    }
    __syncthreads();

    // thread -> (row group g of 4 rows, j-chunk c)
    const int g  = tid & (R - 1);              // 0..3
    const int c  = tid >> 2;                   // 0..127; 4-lane broadcast groups
    const int i0 = blockIdx.x * ROWS_PER_BLOCK + g * R;

    const float4 me0 = tile[i0 + 0];
    const float4 me1 = tile[i0 + 1];
    const float4 me2 = tile[i0 + 2];
    const float4 me3 = tile[i0 + 3];

    float a0 = 0.0f, a1 = 0.0f, a2 = 0.0f, a3 = 0.0f;

#define PAIR(me, acc) {                                      \
        float dx = fabsf(me.x - t.x) - (me.z + t.z);         \
        float dy = fabsf(me.y - t.y) - (me.w + t.w);         \
        float d  = fmaxf(dx, 0.0f) + fmaxf(dy, 0.0f);        \
        float p  = fmaxf(NOTCH_THRESH - d, 0.0f);            \
        acc = fmaf(p, p, acc); }

    // j = jj*128 + c: wave reads 16 consecutive float4 slots (4-lane
    // broadcast each, 2-way bank aliasing = free). ds_read_b128 with
    // immediate offsets after unroll (stride 2048 B).
    #pragma unroll 4
    for (int jj = 0; jj < JPT; ++jj) {
        const float4 t = tile[jj * CCHUNKS + c];
        PAIR(me0, a0)
        PAIR(me1, a1)
        PAIR(me2, a2)
        PAIR(me3, a3)
    }
#undef PAIR

    float acc = (a0 + a1) + (a2 + a3);

    // Deterministic reduction: wave shuffle -> LDS -> per-block partial
    for (int off = 32; off > 0; off >>= 1)
        acc += __shfl_down(acc, off, 64);
    const int wave = tid >> 6;
    const int lane = tid & 63;
    if (lane == 0) red[wave] = acc;
    __syncthreads();
    if (tid == 0) {
        float s = 0.0f;
        #pragma unroll
        for (int w = 0; w < THREADS / 64; ++w) s += red[w];
        partial[blockIdx.x] = s;
    }
}

__global__ __launch_bounds__(256) void notch_final(
    const float* __restrict__ partial, float* __restrict__ out)
{
    __shared__ float red[4];
    const int tid = threadIdx.x;
    float v = partial[tid];   // exactly 256 partials
    for (int off = 32; off > 0; off >>= 1)
        v += __shfl_down(v, off, 64);
    if ((tid & 63) == 0) red[tid >> 6] = v;
    __syncthreads();
    if (tid == 0) {
        const float total = red[0] + red[1] + red[2] + red[3];
        out[0] = (total - 4.0f * (float)N) * 0.5f;
    }
}

extern "C" void kernel_launch(void* const* d_in, const int* in_sizes, int n_in,
                              void* d_out, int out_size, void* d_ws, size_t ws_size,
                              hipStream_t stream) {
    const float* pos = (const float*)d_in[0];
    // d_in[1] = macro_mask (unused by the reference computation)
    const float* sx  = (const float*)d_in[2];
    const float* sy  = (const float*)d_in[3];
    float* out     = (float*)d_out;
    float* partial = (float*)d_ws;   // 256 floats of scratch

    notch_main<<<NBLOCKS, THREADS, 0, stream>>>(pos, sx, sy, partial);
    notch_final<<<1, 256, 0, stream>>>(partial, out);
}